// Round 1
// baseline (353.055 us; speedup 1.0000x reference)
//
#include <hip/hip_runtime.h>
#include <hip/hip_bf16.h>

#define D_FEAT 128

// ---------------------------------------------------------------------------
// Algebraic collapse: all layers before softmax are linear, and SpMM (A·X)
// commutes with right-multiplication: A(XW) = (AX)W. Elementwise row-vector
// scales are diag() right-mults. Hence:
//   logits = A^2 (x @ W_all) + A(1 g^T) + 1 c^T
//   W_all  = diag(w1) Wd1 diag(w2) Wd2 Wout        (128x4)
//   g      = b1^T diag(w2) Wd2 Wout                (4)
//   c      = b2^T Wout + bout                      (4)
// ---------------------------------------------------------------------------

// K1: fold all weights into W_all(128x4), g(4), c(4). One block of 256.
__global__ void precompute_kernel(const float* __restrict__ w1,
                                  const float* __restrict__ Wd1,
                                  const float* __restrict__ b1,
                                  const float* __restrict__ w2,
                                  const float* __restrict__ Wd2,
                                  const float* __restrict__ b2,
                                  const float* __restrict__ Wout,
                                  const float* __restrict__ bout,
                                  float* __restrict__ Wall,
                                  float* __restrict__ g,
                                  float* __restrict__ c)
{
    __shared__ float T2[64 * 4];   // T2[m][j] = w2[m] * sum_p Wd2[m][p] Wout[p][j]
    int t = threadIdx.x;
    {
        int m = t >> 2, j = t & 3;
        float s = 0.f;
        for (int p = 0; p < 32; ++p) s += Wd2[m * 32 + p] * Wout[p * 4 + j];
        T2[t] = w2[m] * s;
    }
    __syncthreads();
    for (int idx = t; idx < 512; idx += 256) {
        int k = idx >> 2, j = idx & 3;
        float s = 0.f;
        for (int m = 0; m < 64; ++m) s += Wd1[k * 64 + m] * T2[m * 4 + j];
        Wall[idx] = w1[k] * s;
    }
    if (t < 4) {
        float s = 0.f;
        for (int m = 0; m < 64; ++m) s += b1[m] * T2[m * 4 + t];
        g[t] = s;
        float s2 = 0.f;
        for (int p = 0; p < 32; ++p) s2 += b2[p] * Wout[p * 4 + t];
        c[t] = s2 + bout[t];
    }
}

// K2: init scatter targets. v := g (so spmm2 sees A v + A 1 g^T), L := c.
__global__ void init_kernel(const float* __restrict__ gp,
                            const float* __restrict__ cp,
                            float4* __restrict__ v4,
                            float4* __restrict__ L4, int n)
{
    int i = blockIdx.x * blockDim.x + threadIdx.x;
    if (i < n) {
        v4[i] = *(const float4*)gp;
        L4[i] = *(const float4*)cp;
    }
}

// K3: u = x @ W_all. One wave handles 2 rows per iteration:
// lane l: half h=l>>5 picks row, q=l&31 covers k = 4q..4q+3 via one float4
// load (wave reads 1 KiB contiguous). W_all rows live in registers (loaded
// once per wave). Cross-lane sum over the 32 lanes of each half.
__global__ void xw_kernel(const float4* __restrict__ x4,
                          const float4* __restrict__ Wall4,
                          float4* __restrict__ u4, int nPairs)
{
    int lane = threadIdx.x & 63;
    int q = lane & 31;
    float4 wa = Wall4[q * 4 + 0];
    float4 wb = Wall4[q * 4 + 1];
    float4 wc = Wall4[q * 4 + 2];
    float4 wd = Wall4[q * 4 + 3];
    int wavesPerBlock = blockDim.x >> 6;
    int gw = blockIdx.x * wavesPerBlock + (threadIdx.x >> 6);
    int nw = gridDim.x * wavesPerBlock;
    for (int rp = gw; rp < nPairs; rp += nw) {
        float4 xv = x4[rp * 64 + lane];
        float4 acc;
        acc.x = xv.x * wa.x + xv.y * wb.x + xv.z * wc.x + xv.w * wd.x;
        acc.y = xv.x * wa.y + xv.y * wb.y + xv.z * wc.y + xv.w * wd.y;
        acc.z = xv.x * wa.z + xv.y * wb.z + xv.z * wc.z + xv.w * wd.z;
        acc.w = xv.x * wa.w + xv.y * wb.w + xv.z * wc.w + xv.w * wd.w;
        // reduce within each 32-lane half (masks < 32 never cross halves)
        for (int m = 16; m >= 1; m >>= 1) {
            acc.x += __shfl_xor(acc.x, m, 64);
            acc.y += __shfl_xor(acc.y, m, 64);
            acc.z += __shfl_xor(acc.z, m, 64);
            acc.w += __shfl_xor(acc.w, m, 64);
        }
        if (q == 0) u4[rp * 2 + (lane >> 5)] = acc;
    }
}

// K4/K5: width-4 edge scatter: out[dst] += in[src]. in is 800 KB -> L2-hot.
__global__ void spmm_kernel(const int* __restrict__ src,
                            const int* __restrict__ dst,
                            const float4* __restrict__ in4,
                            float* __restrict__ out, int nE)
{
    int e = blockIdx.x * blockDim.x + threadIdx.x;
    if (e < nE) {
        int s = src[e], d = dst[e];
        float4 val = in4[s];
        unsafeAtomicAdd(&out[d * 4 + 0], val.x);
        unsafeAtomicAdd(&out[d * 4 + 1], val.y);
        unsafeAtomicAdd(&out[d * 4 + 2], val.z);
        unsafeAtomicAdd(&out[d * 4 + 3], val.w);
    }
}

// K6: softmax over 4 logits per node.
__global__ void softmax_kernel(const float4* __restrict__ L4,
                               float4* __restrict__ out4, int n)
{
    int i = blockIdx.x * blockDim.x + threadIdx.x;
    if (i < n) {
        float4 l = L4[i];
        float m = fmaxf(fmaxf(l.x, l.y), fmaxf(l.z, l.w));
        float ex = __expf(l.x - m);
        float ey = __expf(l.y - m);
        float ez = __expf(l.z - m);
        float ew = __expf(l.w - m);
        float r = 1.f / (ex + ey + ez + ew);
        out4[i] = make_float4(ex * r, ey * r, ez * r, ew * r);
    }
}

extern "C" void kernel_launch(void* const* d_in, const int* in_sizes, int n_in,
                              void* d_out, int out_size, void* d_ws, size_t ws_size,
                              hipStream_t stream)
{
    const float* x    = (const float*)d_in[0];
    const int*   src  = (const int*)d_in[1];
    const int*   dst  = (const int*)d_in[2];
    const float* w1   = (const float*)d_in[3];
    const float* Wd1  = (const float*)d_in[4];
    const float* b1   = (const float*)d_in[5];
    const float* w2   = (const float*)d_in[6];
    const float* Wd2  = (const float*)d_in[7];
    const float* b2   = (const float*)d_in[8];
    const float* Wout = (const float*)d_in[9];
    const float* bout = (const float*)d_in[10];

    const int nE = in_sizes[1];
    const int nN = in_sizes[0] / D_FEAT;   // 50000

    // ws layout (floats): Wall[512] | g[4] | c[4] | pad | u[4N] | v[4N] | L[4N]
    float* ws   = (float*)d_ws;
    float* Wall = ws;
    float* g    = ws + 512;
    float* c    = ws + 516;
    float* u    = ws + 640;          // 16B-aligned
    float* v    = u + (size_t)nN * 4;
    float* L    = v + (size_t)nN * 4;

    precompute_kernel<<<1, 256, 0, stream>>>(w1, Wd1, b1, w2, Wd2, b2, Wout, bout,
                                             Wall, g, c);
    init_kernel<<<(nN + 255) / 256, 256, 0, stream>>>(g, c, (float4*)v, (float4*)L, nN);
    xw_kernel<<<2048, 256, 0, stream>>>((const float4*)x, (const float4*)Wall,
                                        (float4*)u, nN / 2);
    spmm_kernel<<<(nE + 255) / 256, 256, 0, stream>>>(src, dst, (const float4*)u, v, nE);
    spmm_kernel<<<(nE + 255) / 256, 256, 0, stream>>>(src, dst, (const float4*)v, L, nE);
    softmax_kernel<<<(nN + 255) / 256, 256, 0, stream>>>((const float4*)L,
                                                         (float4*)d_out, nN);
}

// Round 2
// 150.740 us; speedup vs baseline: 2.3421x; 2.3421x over previous
//
#include <hip/hip_runtime.h>
#include <hip/hip_bf16.h>

#define D_FEAT 128
#define NP 128              // nodes per partition
#define P_PARTS 391         // ceil(50000/128)
#define CAP 2048            // edge capacity per partition (mean 1536, +13 sigma)
#define EPB 4096            // edges per bucket block

// ---------------------------------------------------------------------------
// logits = A^2 (x @ W_all) + A(1 g^T) + 1 c^T ;  out = softmax(logits)
//   W_all = diag(w1) Wd1 diag(w2) Wd2 Wout  (128x4),  g = b1^T diag(w2) Wd2 Wout,
//   c = b2^T Wout + bout.
// SpMM done per 128-node destination partition with LDS accumulation —
// zero per-edge global atomics (memory-side fp32 atomics cost ~32B HBM RMW
// each; that was 75MB WRITE_SIZE / 128us per layer in round 1).
// ---------------------------------------------------------------------------

// K1: fold weights; also zero the partition fill counters for this launch.
__global__ void precompute_kernel(const float* __restrict__ w1,
                                  const float* __restrict__ Wd1,
                                  const float* __restrict__ b1,
                                  const float* __restrict__ w2,
                                  const float* __restrict__ Wd2,
                                  const float* __restrict__ b2,
                                  const float* __restrict__ Wout,
                                  const float* __restrict__ bout,
                                  float* __restrict__ Wall,
                                  float* __restrict__ g,
                                  float* __restrict__ c,
                                  int* __restrict__ partFill)
{
    __shared__ float T2[64 * 4];   // T2[m][j] = w2[m] * sum_p Wd2[m][p] Wout[p][j]
    int t = threadIdx.x;
    for (int i = t; i < P_PARTS; i += 256) partFill[i] = 0;
    {
        int m = t >> 2, j = t & 3;
        float s = 0.f;
        for (int p = 0; p < 32; ++p) s += Wd2[m * 32 + p] * Wout[p * 4 + j];
        T2[t] = w2[m] * s;
    }
    __syncthreads();
    for (int idx = t; idx < 512; idx += 256) {
        int k = idx >> 2, j = idx & 3;
        float s = 0.f;
        for (int m = 0; m < 64; ++m) s += Wd1[k * 64 + m] * T2[m * 4 + j];
        Wall[idx] = w1[k] * s;
    }
    if (t < 4) {
        float s = 0.f;
        for (int m = 0; m < 64; ++m) s += b1[m] * T2[m * 4 + t];
        g[t] = s;
        float s2 = 0.f;
        for (int p = 0; p < 32; ++p) s2 += b2[p] * Wout[p * 4 + t];
        c[t] = s2 + bout[t];
    }
}

// K2: u = x @ W_all, thread-per-row, W_all broadcast from LDS.
__global__ void xw_kernel(const float4* __restrict__ x4,
                          const float4* __restrict__ Wall4,
                          float4* __restrict__ u4, int nRows)
{
    __shared__ float4 W[128];      // W[k] = row k of W_all (4 floats)
    int t = threadIdx.x;
    if (t < 128) W[t] = Wall4[t];
    __syncthreads();
    int r = blockIdx.x * blockDim.x + t;
    if (r >= nRows) return;
    float4 acc = make_float4(0.f, 0.f, 0.f, 0.f);
    #pragma unroll 8
    for (int k4 = 0; k4 < 32; ++k4) {
        float4 xv = x4[(size_t)r * 32 + k4];
        float4 w0 = W[4 * k4 + 0];
        float4 w1 = W[4 * k4 + 1];
        float4 w2 = W[4 * k4 + 2];
        float4 w3 = W[4 * k4 + 3];
        acc.x += xv.x * w0.x + xv.y * w1.x + xv.z * w2.x + xv.w * w3.x;
        acc.y += xv.x * w0.y + xv.y * w1.y + xv.z * w2.y + xv.w * w3.y;
        acc.z += xv.x * w0.z + xv.y * w1.z + xv.z * w2.z + xv.w * w3.z;
        acc.w += xv.x * w0.w + xv.y * w1.w + xv.z * w2.w + xv.w * w3.w;
    }
    u4[r] = acc;
}

// K3: bucket edges by destination partition (dst >> 7).
// Per-block LDS histogram -> one chunk-reserve global atomic per partition
// -> rank via LDS countdown -> packed write (src | dstLocal<<16).
__global__ void bucket_kernel(const int* __restrict__ src,
                              const int* __restrict__ dst,
                              int* __restrict__ partFill,
                              int* __restrict__ edgeBuf, int nE)
{
    __shared__ int hist[P_PARTS];
    __shared__ int base[P_PARTS];
    int t = threadIdx.x;
    for (int p = t; p < P_PARTS; p += 256) hist[p] = 0;
    __syncthreads();
    int beg = blockIdx.x * EPB + t;
    int end = min(blockIdx.x * EPB + EPB, nE);
    for (int i = beg; i < end; i += 256)
        atomicAdd(&hist[dst[i] >> 7], 1);
    __syncthreads();
    for (int p = t; p < P_PARTS; p += 256) {
        int h = hist[p];
        base[p] = h ? atomicAdd(&partFill[p], h) : 0;
    }
    __syncthreads();
    for (int i = beg; i < end; i += 256) {
        int d = dst[i];
        int p = d >> 7;
        int rank = atomicSub(&hist[p], 1) - 1;   // unique in [0, h)
        int pos = base[p] + rank;
        if (pos < CAP)
            edgeBuf[p * CAP + pos] = src[i] | ((d & 127) << 16);
    }
}

// K4/K5: one block per 128-node partition. Accumulate A*in in LDS,
// add the constant vector, optionally softmax, coalesced store.
__global__ void spmm_part_kernel(const int* __restrict__ partFill,
                                 const int* __restrict__ edgeBuf,
                                 const float4* __restrict__ in4,
                                 const float* __restrict__ addvec,
                                 float4* __restrict__ out4,
                                 int nN, int doSoftmax)
{
    __shared__ float acc[NP * 4];
    int t = threadIdx.x, p = blockIdx.x;
    acc[t] = 0.f;
    acc[t + 256] = 0.f;
    __syncthreads();
    int n = min(partFill[p], CAP);
    const int* eb = edgeBuf + p * CAP;
    for (int i = t; i < n; i += 256) {
        int e = eb[i];
        float4 val = in4[e & 0xFFFF];
        int dl = e >> 16;
        atomicAdd(&acc[dl * 4 + 0], val.x);
        atomicAdd(&acc[dl * 4 + 1], val.y);
        atomicAdd(&acc[dl * 4 + 2], val.z);
        atomicAdd(&acc[dl * 4 + 3], val.w);
    }
    __syncthreads();
    if (t < NP) {
        int node = p * NP + t;
        if (node < nN) {
            float4 a = ((const float4*)acc)[t];
            float4 cv = *(const float4*)addvec;
            float lx = a.x + cv.x, ly = a.y + cv.y;
            float lz = a.z + cv.z, lw = a.w + cv.w;
            if (doSoftmax) {
                float m = fmaxf(fmaxf(lx, ly), fmaxf(lz, lw));
                float ex = __expf(lx - m);
                float ey = __expf(ly - m);
                float ez = __expf(lz - m);
                float ew = __expf(lw - m);
                float r = 1.f / (ex + ey + ez + ew);
                out4[node] = make_float4(ex * r, ey * r, ez * r, ew * r);
            } else {
                out4[node] = make_float4(lx, ly, lz, lw);
            }
        }
    }
}

extern "C" void kernel_launch(void* const* d_in, const int* in_sizes, int n_in,
                              void* d_out, int out_size, void* d_ws, size_t ws_size,
                              hipStream_t stream)
{
    const float* x    = (const float*)d_in[0];
    const int*   src  = (const int*)d_in[1];
    const int*   dst  = (const int*)d_in[2];
    const float* w1   = (const float*)d_in[3];
    const float* Wd1  = (const float*)d_in[4];
    const float* b1   = (const float*)d_in[5];
    const float* w2   = (const float*)d_in[6];
    const float* Wd2  = (const float*)d_in[7];
    const float* b2   = (const float*)d_in[8];
    const float* Wout = (const float*)d_in[9];
    const float* bout = (const float*)d_in[10];

    const int nE = in_sizes[1];
    const int nN = in_sizes[0] / D_FEAT;   // 50000

    // ws layout (floats): Wall[512] | g[4] | c[4] | pad->640 | u[4N] | v[4N]
    //                     | partFill[512 ints] | edgeBuf[P_PARTS*CAP ints]
    float* ws   = (float*)d_ws;
    float* Wall = ws;
    float* g    = ws + 512;
    float* c    = ws + 516;
    float* u    = ws + 640;                       // 16B aligned
    float* v    = u + (size_t)nN * 4;             // 16B aligned
    int* partFill = (int*)(v + (size_t)nN * 4);
    int* edgeBuf  = partFill + 512;

    precompute_kernel<<<1, 256, 0, stream>>>(w1, Wd1, b1, w2, Wd2, b2, Wout, bout,
                                             Wall, g, c, partFill);
    xw_kernel<<<(nN + 255) / 256, 256, 0, stream>>>((const float4*)x,
                                                    (const float4*)Wall,
                                                    (float4*)u, nN);
    bucket_kernel<<<(nE + EPB - 1) / EPB, 256, 0, stream>>>(src, dst, partFill,
                                                            edgeBuf, nE);
    spmm_part_kernel<<<P_PARTS, 256, 0, stream>>>(partFill, edgeBuf,
                                                  (const float4*)u, g,
                                                  (float4*)v, nN, 0);
    spmm_part_kernel<<<P_PARTS, 256, 0, stream>>>(partFill, edgeBuf,
                                                  (const float4*)v, c,
                                                  (float4*)d_out, nN, 1);
}

// Round 3
// 139.912 us; speedup vs baseline: 2.5234x; 1.0774x over previous
//
#include <hip/hip_runtime.h>
#include <hip/hip_bf16.h>

#define D_FEAT 128
#define NP 64                // nodes per partition
#define NP_SHIFT 6
#define P_PARTS 782          // ceil(50000/64)
#define CAP 1024             // edges per partition: mean 768, sd ~28 -> +9 sigma
#define EPB 2048             // edges per bucket block

// ---------------------------------------------------------------------------
// logits = A^2 (x @ W_all) + A(1 g^T) + 1 c^T ;  out = softmax(logits)
//   W_all = diag(w1) Wd1 diag(w2) Wd2 Wout  (128x4)
//   g = b1^T diag(w2) Wd2 Wout,  c = b2^T Wout + bout
// K1 fuses: weight-fold (recomputed per xw block, ~200 cyc), u = x@W_all
// (thread-per-row), and edge bucketing by dst partition (counting sort into
// edgeBuf). K2/K3: one block per 64-node partition, LDS accumulate, no
// global atomics on the hot path.
// ---------------------------------------------------------------------------

__global__ __launch_bounds__(256) void fused_xw_bucket_kernel(
    const float4* __restrict__ x4,
    const int* __restrict__ src,
    const int* __restrict__ dst,
    const float* __restrict__ w1,  const float* __restrict__ Wd1,
    const float* __restrict__ b1,  const float* __restrict__ w2,
    const float* __restrict__ Wd2, const float* __restrict__ b2,
    const float* __restrict__ Wout, const float* __restrict__ bout,
    int* __restrict__ partFill, int* __restrict__ edgeBuf,
    float* __restrict__ gc, float4* __restrict__ u4,
    int nN, int nE, int xwBlocks)
{
    __shared__ int sm[2 * P_PARTS];          // bucket: hist+base; xw: T2+Wall
    int t = threadIdx.x;

    if ((int)blockIdx.x < xwBlocks) {
        // ---- inline weight fold ----
        float* T2   = (float*)sm;            // 64x4
        float* Wall = (float*)sm + 256;      // 128x4
        {
            int m = t >> 2, j = t & 3;
            float s = 0.f;
            for (int p = 0; p < 32; ++p) s += Wd2[m * 32 + p] * Wout[p * 4 + j];
            T2[t] = w2[m] * s;
        }
        __syncthreads();
        for (int idx = t; idx < 512; idx += 256) {
            int k = idx >> 2, j = idx & 3;
            float s = 0.f;
            for (int m = 0; m < 64; ++m) s += Wd1[k * 64 + m] * T2[m * 4 + j];
            Wall[idx] = w1[k] * s;
        }
        if (blockIdx.x == 0 && t < 4) {      // publish g, c for K2/K3
            float s = 0.f;
            for (int m = 0; m < 64; ++m) s += b1[m] * T2[m * 4 + t];
            gc[t] = s;
            float s2 = 0.f;
            for (int p = 0; p < 32; ++p) s2 += b2[p] * Wout[p * 4 + t];
            gc[4 + t] = s2 + bout[t];
        }
        __syncthreads();
        // ---- u = x @ W_all, thread-per-row ----
        int r = blockIdx.x * 256 + t;
        if (r < nN) {
            const float4* W = (const float4*)Wall;
            float4 acc = make_float4(0.f, 0.f, 0.f, 0.f);
            #pragma unroll 8
            for (int k4 = 0; k4 < 32; ++k4) {
                float4 xv = x4[(size_t)r * 32 + k4];
                float4 w0 = W[4 * k4 + 0];
                float4 wv1 = W[4 * k4 + 1];
                float4 wv2 = W[4 * k4 + 2];
                float4 wv3 = W[4 * k4 + 3];
                acc.x += xv.x * w0.x + xv.y * wv1.x + xv.z * wv2.x + xv.w * wv3.x;
                acc.y += xv.x * w0.y + xv.y * wv1.y + xv.z * wv2.y + xv.w * wv3.y;
                acc.z += xv.x * w0.z + xv.y * wv1.z + xv.z * wv2.z + xv.w * wv3.z;
                acc.w += xv.x * w0.w + xv.y * wv1.w + xv.z * wv2.w + xv.w * wv3.w;
            }
            u4[r] = acc;
        }
    } else {
        // ---- bucket 2048 edges by dst partition ----
        int b = blockIdx.x - xwBlocks;
        int* hist = sm;
        int* base = sm + P_PARTS;
        for (int p = t; p < P_PARTS; p += 256) hist[p] = 0;
        __syncthreads();
        int beg = b * EPB + t;
        int end = min(b * EPB + EPB, nE);
        for (int i = beg; i < end; i += 256)
            atomicAdd(&hist[dst[i] >> NP_SHIFT], 1);
        __syncthreads();
        for (int p = t; p < P_PARTS; p += 256) {
            int h = hist[p];
            base[p] = h ? atomicAdd(&partFill[p], h) : 0;
        }
        __syncthreads();
        for (int i = beg; i < end; i += 256) {
            int d = dst[i];
            int p = d >> NP_SHIFT;
            int rank = atomicSub(&hist[p], 1) - 1;
            int pos = base[p] + rank;
            if (pos < CAP)
                edgeBuf[p * CAP + pos] = src[i] | ((d & (NP - 1)) << 16);
        }
    }
}

// One block per 64-node partition: gather + LDS accumulate + epilogue.
__global__ __launch_bounds__(256) void spmm_part_kernel(
    const int* __restrict__ partFill,
    const int* __restrict__ edgeBuf,
    const float4* __restrict__ in4,
    const float* __restrict__ gc, int gcOff,
    float4* __restrict__ out4, int nN, int doSoftmax)
{
    __shared__ float acc[NP * 4];            // 256 floats
    int t = threadIdx.x, p = blockIdx.x;
    acc[t] = 0.f;
    __syncthreads();
    int n = min(partFill[p], CAP);
    const int* eb = edgeBuf + p * CAP;
    for (int i = t; i < n; i += 256) {
        int e = eb[i];
        float4 val = in4[e & 0xFFFF];
        int dl = e >> 16;
        atomicAdd(&acc[dl * 4 + 0], val.x);
        atomicAdd(&acc[dl * 4 + 1], val.y);
        atomicAdd(&acc[dl * 4 + 2], val.z);
        atomicAdd(&acc[dl * 4 + 3], val.w);
    }
    __syncthreads();
    if (t < NP) {
        int node = p * NP + t;
        if (node < nN) {
            float4 a = ((const float4*)acc)[t];
            float lx = a.x + gc[gcOff + 0];
            float ly = a.y + gc[gcOff + 1];
            float lz = a.z + gc[gcOff + 2];
            float lw = a.w + gc[gcOff + 3];
            if (doSoftmax) {
                float m = fmaxf(fmaxf(lx, ly), fmaxf(lz, lw));
                float ex = __expf(lx - m);
                float ey = __expf(ly - m);
                float ez = __expf(lz - m);
                float ew = __expf(lw - m);
                float r = 1.f / (ex + ey + ez + ew);
                out4[node] = make_float4(ex * r, ey * r, ez * r, ew * r);
            } else {
                out4[node] = make_float4(lx, ly, lz, lw);
            }
        }
    }
}

extern "C" void kernel_launch(void* const* d_in, const int* in_sizes, int n_in,
                              void* d_out, int out_size, void* d_ws, size_t ws_size,
                              hipStream_t stream)
{
    const float* x    = (const float*)d_in[0];
    const int*   src  = (const int*)d_in[1];
    const int*   dst  = (const int*)d_in[2];
    const float* w1   = (const float*)d_in[3];
    const float* Wd1  = (const float*)d_in[4];
    const float* b1   = (const float*)d_in[5];
    const float* w2   = (const float*)d_in[6];
    const float* Wd2  = (const float*)d_in[7];
    const float* b2   = (const float*)d_in[8];
    const float* Wout = (const float*)d_in[9];
    const float* bout = (const float*)d_in[10];

    const int nE = in_sizes[1];
    const int nN = in_sizes[0] / D_FEAT;     // 50000

    // ws layout (floats): gc[8] pad->16 | u[4N] | v[4N] | partFill | edgeBuf
    float* ws = (float*)d_ws;
    float* gc = ws;
    float* u  = ws + 16;                          // 64B aligned
    float* v  = u + (size_t)nN * 4;
    int* partFill = (int*)(v + (size_t)nN * 4);
    int* edgeBuf  = partFill + ((P_PARTS + 63) & ~63);

    const int xwBlocks = (nN + 255) / 256;        // 196
    const int bkBlocks = (nE + EPB - 1) / EPB;    // 293

    hipMemsetAsync(partFill, 0, P_PARTS * sizeof(int), stream);
    fused_xw_bucket_kernel<<<xwBlocks + bkBlocks, 256, 0, stream>>>(
        (const float4*)x, src, dst, w1, Wd1, b1, w2, Wd2, b2, Wout, bout,
        partFill, edgeBuf, gc, (float4*)u, nN, nE, xwBlocks);
    spmm_part_kernel<<<P_PARTS, 256, 0, stream>>>(partFill, edgeBuf,
                                                  (const float4*)u, gc, 0,
                                                  (float4*)v, nN, 0);
    spmm_part_kernel<<<P_PARTS, 256, 0, stream>>>(partFill, edgeBuf,
                                                  (const float4*)v, gc, 4,
                                                  (float4*)d_out, nN, 1);
}